// Round 4
// baseline (329.769 us; speedup 1.0000x reference)
//
#include <hip/hip_runtime.h>

// LatticeStyleConv R7: StyleGAN2-modulated 5-point stencil conv, bf16 MFMA.
// bs=8, ci=co=256, H=W=128.
//
// R7: faithful 8-phase-template port (5 phases/ck, T2+T3+T4+T5+T1).
//  * conv3: per ck, 5 two-barrier phases (one per stencil tap s):
//      {af-prefetch(phase+1) | 4x ds_read_b128(s) | stage-slice(ck+1)}
//      -> s_barrier -> masks -> setprio(1) 16 MFMA setprio(0) -> s_barrier.
//    Stage DMAs (8 chunks, issued phases 0-1) stay in flight across all
//    phase barriers; the ONLY vmcnt(0) is at the ck boundary, where all
//    outstanding vmem (stage ck+1, af next) is needed immediately and was
//    issued >=3 phases earlier => zero-waste drain. af prefetched one phase
//    ahead -> its wait is a counted vmcnt (compiler-exact), never a drain.
//  * T2: quad-major LDS rows (granule = quad*80+px, row stride 5120B) via
//    per-lane pre-permuted GLOBAL source (DMA dest linear, rule #21): every
//    8-lane phase group reads 8 consecutive granules -> all 8 bank groups,
//    zero conflicts by construction. LDS 2x30720=61440B.
//  * T1: XCD-chunked block remap (2048%8==0, bijective): each XCD works one
//    batch b -> per-XCD L2 holds only that b's x plane + wfrag slab.
// Layouts (guide §3 m89/m91): A[m=l15][k=quad*8+j]; B[n=l15][k=quad*8+j];
// C/D col=l15, row=quad*4+reg.

typedef short v8s __attribute__((ext_vector_type(8)));
typedef float v4f __attribute__((ext_vector_type(4)));
typedef int   v4i __attribute__((ext_vector_type(4)));

#define BS 8
#define CI 256
#define CO 256
#define HH 128
#define WW 128

#define WF_CK 10240          // shorts per (b,ot,ck) A-frag slab
#define R7STR_B 5120         // conv3 LDS row stride bytes (4 quads * 80 px * 16B)
#define XB7_I 7680           // ints per x-tile buffer (6 rows * 1280)
#define XB7_B 30720          // bytes per x-tile buffer

#define GLOAD_LDS16(g, l)                                                  \
    __builtin_amdgcn_global_load_lds(                                      \
        (__attribute__((address_space(1))) void*)(g),                      \
        (__attribute__((address_space(3))) void*)(l), 16, 0, 0)

__device__ __forceinline__ unsigned short f2bf(float f) {
    unsigned u = __builtin_bit_cast(unsigned, f);
    u += 0x7FFFu + ((u >> 16) & 1u);   // RNE (inputs finite)
    return (unsigned short)(u >> 16);
}

// -------- fused prep: blocks [0,2048) weight-prep, [2048,10240) x-transpose --
__global__ __launch_bounds__(256) void prep_kernel(const float* __restrict__ x,
                                                   const float* __restrict__ y,
                                                   const float* __restrict__ wgt,
                                                   short* __restrict__ wfrag,
                                                   unsigned int* __restrict__ xt) {
    __shared__ float tr[32 * 132];     // [c][px], stride 132 floats
    __shared__ float red[4];

    if (blockIdx.x < 2048) {
        // ---- wprep2: fused demod + modulated weights -> A-frag layout ----
        const int bo = blockIdx.x;
        const int b = bo >> 8, o = bo & 255;
        const int ci = threadIdx.x;
        const float ym = y[b * CI + ci] + 1.0f;
        const float* wp = wgt + (o * CI + ci) * 5;
        float w[5];
        float s2 = 0.f;
        #pragma unroll
        for (int s = 0; s < 5; ++s) { w[s] = wp[s]; s2 += w[s] * w[s]; }
        float ss = ym * ym * s2;
        #pragma unroll
        for (int off = 32; off > 0; off >>= 1) ss += __shfl_down(ss, off);
        if ((threadIdx.x & 63) == 0) red[threadIdx.x >> 6] = ss;
        __syncthreads();
        const float tot = red[0] + red[1] + red[2] + red[3];
        const float scale = ym * rsqrtf(tot + 1e-6f);
        const int ot = o >> 6, mt = (o >> 4) & 3, m = o & 15;
        const int ck = ci >> 5, quad = (ci >> 3) & 3, j = ci & 7;
        size_t base = ((size_t)(b * 4 + ot) * 8 + ck) * WF_CK + quad * 128 + m * 8 + j;
        #pragma unroll
        for (int s = 0; s < 5; ++s)
            wfrag[base + (size_t)(s * 4 + mt) * 512] = (short)f2bf(w[s] * scale);
    } else {
        // ---- xprep: x fp32 [b][ci][h][w] -> bf16 x_t[b][ck][h][w][32ch] ----
        const int bid = blockIdx.x - 2048;     // (b*8 + ck)*128 + h
        const int b  = bid >> 10;
        const int ck = (bid >> 7) & 7;
        const int h  = bid & 127;
        const int tid = threadIdx.x;
        // vectorized loads: 4 x dwordx4 per thread, b128 LDS writes
        #pragma unroll
        for (int i = 0; i < 4; ++i) {
            int q  = tid + i * 256;            // 0..1023
            int c  = q >> 5;                   // 0..31
            int qp = q & 31;                   // 0..31 (px quad)
            v4f v = *(const v4f*)&x[((size_t)(b * CI + ck * 32 + c) * HH + h) * WW
                                    + qp * 4];
            *(v4f*)&tr[c * 132 + qp * 4] = v;
        }
        __syncthreads();
        const int px = tid >> 1, half = tid & 1;
        unsigned pk[8];
        #pragma unroll
        for (int k = 0; k < 8; ++k) {
            float f0 = tr[(half * 16 + 2 * k)     * 132 + px];
            float f1 = tr[(half * 16 + 2 * k + 1) * 132 + px];
            pk[k] = (unsigned)f2bf(f0) | ((unsigned)f2bf(f1) << 16);
        }
        unsigned int* dst = xt + ((size_t)((b * 8 + ck) * 16384 + h * 128 + px)) * 16
                               + half * 8;
        *(v4i*)dst       = (v4i){(int)pk[0], (int)pk[1], (int)pk[2], (int)pk[3]};
        *(v4i*)(dst + 4) = (v4i){(int)pk[4], (int)pk[5], (int)pk[6], (int)pk[7]};
    }
}

// -------- wprep2 standalone (mid-path fallback) --------
__global__ __launch_bounds__(256) void wprep2_kernel(const float* __restrict__ y,
                                                     const float* __restrict__ wgt,
                                                     short* __restrict__ wfrag) {
    const int bo = blockIdx.x;
    const int b = bo >> 8, o = bo & 255;
    const int ci = threadIdx.x;
    const float ym = y[b * CI + ci] + 1.0f;
    const float* wp = wgt + (o * CI + ci) * 5;
    float w[5];
    float s2 = 0.f;
    #pragma unroll
    for (int s = 0; s < 5; ++s) { w[s] = wp[s]; s2 += w[s] * w[s]; }
    float ss = ym * ym * s2;
    #pragma unroll
    for (int off = 32; off > 0; off >>= 1) ss += __shfl_down(ss, off);
    __shared__ float red[4];
    if ((threadIdx.x & 63) == 0) red[threadIdx.x >> 6] = ss;
    __syncthreads();
    const float tot = red[0] + red[1] + red[2] + red[3];
    const float scale = ym * rsqrtf(tot + 1e-6f);
    const int ot = o >> 6, mt = (o >> 4) & 3, m = o & 15;
    const int ck = ci >> 5, quad = (ci >> 3) & 3, j = ci & 7;
    size_t base = ((size_t)(b * 4 + ot) * 8 + ck) * WF_CK + quad * 128 + m * 8 + j;
    #pragma unroll
    for (int s = 0; s < 5; ++s)
        wfrag[base + (size_t)(s * 4 + mt) * 512] = (short)f2bf(w[s] * scale);
}

// -------- conv3: 5-phase two-barrier schedule, conflict-free LDS --------

#define PHASE(S, STG, WFN, SN)                                                 \
  {                                                                            \
    v8s pafN[4];                                                               \
    _Pragma("unroll")                                                          \
    for (int mt = 0; mt < 4; ++mt)                                             \
      pafN[mt] = *(const v8s*)((WFN) + (size_t)(((SN) * 4 + mt) * 4 + quad)    \
                                           * 128 + l15 * 8);                   \
    v4i bi[4];                                                                 \
    _Pragma("unroll")                                                          \
    for (int nt = 0; nt < 4; ++nt)                                             \
      bi[nt] = *(const v4i*)&xb[boff_i[(S)][nt]];                              \
    if ((STG) == 1) stage4(ckn, bufn, 0);                                      \
    if ((STG) == 2) stage4(ckn, bufn, 4);                                      \
    __builtin_amdgcn_sched_barrier(0);                                         \
    __builtin_amdgcn_s_barrier();                                              \
    __builtin_amdgcn_sched_barrier(0);                                         \
    if ((S) == 0) { if (topz) { bi[0] = z4; bi[1] = z4; bi[2] = z4; bi[3] = z4; } } \
    if ((S) == 4) { if (botz) { bi[0] = z4; bi[1] = z4; bi[2] = z4; bi[3] = z4; } } \
    if ((S) == 1) { if (lzm) bi[0] = z4; }                                     \
    if ((S) == 3) { if (rzm) bi[3] = z4; }                                     \
    __builtin_amdgcn_s_setprio(1);                                             \
    _Pragma("unroll")                                                          \
    for (int nt = 0; nt < 4; ++nt) {                                           \
      v8s bfr = __builtin_bit_cast(v8s, bi[nt]);                               \
      _Pragma("unroll")                                                        \
      for (int mt = 0; mt < 4; ++mt)                                           \
        acc[mt][nt] = __builtin_amdgcn_mfma_f32_16x16x32_bf16(                 \
            pafC[mt], bfr, acc[mt][nt], 0, 0, 0);                              \
    }                                                                          \
    __builtin_amdgcn_s_setprio(0);                                             \
    if ((S) == 4) {                                                            \
      __builtin_amdgcn_sched_barrier(0);                                       \
      asm volatile("s_waitcnt vmcnt(0)" ::: "memory");                         \
    }                                                                          \
    __builtin_amdgcn_s_barrier();                                              \
    _Pragma("unroll")                                                          \
    for (int mt = 0; mt < 4; ++mt) pafC[mt] = pafN[mt];                        \
  }

__global__ __launch_bounds__(256, 2) void conv3_kernel(const char* __restrict__ xt,
                                                       const short* __restrict__ wfrag,
                                                       float* __restrict__ out) {
    // T1: XCD-chunked bijective remap (2048 % 8 == 0)
    const int flat = blockIdx.x + 64 * (blockIdx.y + 4 * blockIdx.z);
    const int wrk  = (flat & 7) * 256 + (flat >> 3);
    const int b    = wrk >> 8;
    const int ot   = (wrk >> 6) & 3;
    const int st   = wrk & 63;
    const int oBase = ot * 64;
    const int r0    = (st >> 1) * 4;
    const int c0    = (st & 1) * 64;
    const bool left = (c0 == 0);

    const int tid  = threadIdx.x;
    const int wid  = tid >> 6;
    const int lane = tid & 63;
    const int l15  = lane & 15;
    const int quad = lane >> 4;

    __shared__ __align__(16) int xs[2 * XB7_I];    // 61440 B

    v4f acc[4][4];
    #pragma unroll
    for (int a = 0; a < 4; ++a)
        #pragma unroll
        for (int n = 0; n < 4; ++n) acc[a][n] = (v4f){0.f, 0.f, 0.f, 0.f};

    const int row = r0 + wid;
    const short* wfb = wfrag + (size_t)(b * 4 + ot) * 8 * WF_CK;
    const int gstartB = (c0 - 1) * 64;               // uniform (left: px-1 garbage)

    // register-side halo masks (staging is branch-free and uniform)
    const bool rzm  = (!left) && (l15 == 15);        // right edge (s3,nt3 slot65)
    const bool lzm  = left && (l15 == 0);            // left edge  (s1,nt0 slot0)
    const bool topz = (r0 == 0)      && (wid == 0);  // s0 tap of output row 0
    const bool botz = (r0 == HH - 4) && (wid == 3);  // s4 tap of output row 127
    const v4i z4 = (v4i){0, 0, 0, 0};

    const int dh[5] = {-1, 0, 0, 0, 1};
    const int dw[5] = { 0,-1, 0, 1, 0};

    // ---- staging offsets: 32 chunks (30 real + 2 dup), 8 per wave.
    // LDS layout per row: quad-major, granule = quad*80 + px (conflict-free
    // reads). DMA dest linear; SOURCE carries the permutation (rule #21).
    int goff[8], loff[8];
    #pragma unroll
    for (int k = 0; k < 8; ++k) {
        int q  = wid + 4 * k;                 // 0..31
        int qq = q < 30 ? q : q - 2;          // dummies duplicate chunks 28,29
        int rr = qq / 5, t = qq - rr * 5;
        int g  = t * 64 + lane;               // dest granule within row (0..319)
        int qd = g / 80, px = g - qd * 80;
        int gr = r0 - 1 + rr;
        gr = gr < 0 ? 0 : (gr > 127 ? 127 : gr);   // clamp; masked in regs
        goff[k] = gr * 8192 + gstartB + px * 64 + qd * 16;
        loff[k] = rr * R7STR_B + g * 16;
    }

    // ---- B-read offsets (int index), conflict-free by construction ----
    int boff_i[5][4];
    #pragma unroll
    for (int s = 0; s < 5; ++s) {
        const int xrow = wid + 1 + dh[s];
        const int xc0  = 1 + dw[s];
        #pragma unroll
        for (int nt = 0; nt < 4; ++nt)
            boff_i[s][nt] = xrow * 1280 + quad * 320 + (nt * 16 + l15 + xc0) * 4;
    }

    auto stage4 = [&](int ckk, int bufsel, int k0) {
        const char* planep = xt + (((size_t)(b * 8 + ckk)) << 20);
        char* lbase = (char*)xs + bufsel * XB7_B;
        #pragma unroll
        for (int kk = 0; kk < 4; ++kk)
            GLOAD_LDS16(planep + goff[k0 + kk], lbase + loff[k0 + kk]);
    };

    // ---- prologue: stage ck0 + preload af(ck0, s0), drain, barrier ----
    stage4(0, 0, 0);
    stage4(0, 0, 4);
    v8s pafC[4];
    #pragma unroll
    for (int mt = 0; mt < 4; ++mt)
        pafC[mt] = *(const v8s*)(wfb + (size_t)(mt * 4 + quad) * 128 + l15 * 8);
    asm volatile("s_waitcnt vmcnt(0)" ::: "memory");
    __builtin_amdgcn_s_barrier();

    for (int ck = 0; ck < 7; ++ck) {
        const short* wfc  = wfb + (size_t)ck * WF_CK;
        const short* wfcN = wfc + WF_CK;
        const int*   xb   = xs + (ck & 1) * XB7_I;
        const int    bufn = (ck + 1) & 1;
        const int    ckn  = ck + 1;
        PHASE(0, 1, wfc, 1)
        PHASE(1, 2, wfc, 2)
        PHASE(2, 0, wfc, 3)
        PHASE(3, 0, wfc, 4)
        PHASE(4, 0, wfcN, 0)
    }
    {   // ---- epilogue ck=7: no staging; af-next loads are benign dummies ----
        const short* wfc  = wfb + (size_t)7 * WF_CK;
        const int*   xb   = xs + XB7_I;
        const int    bufn = 0;
        const int    ckn  = 0;
        (void)bufn; (void)ckn;
        PHASE(0, 0, wfc, 1)
        PHASE(1, 0, wfc, 2)
        PHASE(2, 0, wfc, 3)
        PHASE(3, 0, wfc, 4)
        PHASE(4, 0, wfc, 0)
    }

    #pragma unroll
    for (int mt = 0; mt < 4; ++mt)
        #pragma unroll
        for (int nt = 0; nt < 4; ++nt)
            #pragma unroll
            for (int r = 0; r < 4; ++r) {
                int o = oBase + mt * 16 + quad * 4 + r;
                int c = c0 + nt * 16 + l15;
                out[((size_t)(b * CO + o) * HH + row) * WW + c] = acc[mt][nt][r];
            }
}

// ================= R2 conv (mid fallback) =================
__global__ __launch_bounds__(256, 4) void conv_kernel(const float* __restrict__ x,
                                                      const short* __restrict__ wfrag,
                                                      float* __restrict__ out) {
    const int b     = blockIdx.z;
    const int ot    = blockIdx.y;
    const int oBase = ot * 64;
    const int st    = blockIdx.x;
    const int r0    = (st >> 1) * 4;
    const int c0    = (st & 1) * 64;
    const int tid  = threadIdx.x;
    const int wid  = tid >> 6;
    const int lane = tid & 63;
    const int l15  = lane & 15;
    const int quad = lane >> 4;
    #define PXS 20
    __shared__ __align__(16) int xs[6 * 66 * PXS];
    v4f acc[4][4];
    #pragma unroll
    for (int a = 0; a < 4; ++a)
        #pragma unroll
        for (int n = 0; n < 4; ++n) acc[a][n] = (v4f){0.f, 0.f, 0.f, 0.f};
    const int row = r0 + wid;
    const short* wfb = wfrag + (size_t)(b * 4 + ot) * 8 * WF_CK;
    const int dh[5] = {-1, 0, 0, 0, 1};
    const int dw[5] = { 0,-1, 0, 1, 0};
    for (int ck = 0; ck < 8; ++ck) {
        const int ic0 = ck * 32;
        #pragma unroll
        for (int t = 0; t < 6; ++t) {
            int idx = tid + t * 256;
            int cp  = idx & 15;
            int tmp = idx >> 4;
            int cq  = tmp & 15;
            int rr  = tmp >> 4;
            int gr  = r0 - 1 + rr;
            v4f a0 = (v4f){0.f, 0.f, 0.f, 0.f}, a1 = a0;
            if (gr >= 0 && gr < HH) {
                const float* xp = x + ((size_t)(b * CI + ic0 + cp * 2) * HH + gr) * WW
                                    + (c0 + cq * 4);
                a0 = *(const v4f*)xp;
                a1 = *(const v4f*)(xp + HH * WW);
            }
            int base = (rr * 66 + cq * 4 + 1) * PXS + cp;
            #pragma unroll
            for (int k = 0; k < 4; ++k)
                xs[base + k * PXS] =
                    (int)((unsigned)f2bf(a0[k]) | ((unsigned)f2bf(a1[k]) << 16));
        }
        if (tid < 192) {
            int cp   = tid & 15;
            int tmp  = tid >> 4;
            int side = (tmp >= 6) ? 1 : 0;
            int rr   = tmp - 6 * side;
            int gr   = r0 - 1 + rr;
            int gc   = side ? (c0 + 64) : (c0 - 1);
            float v0 = 0.f, v1 = 0.f;
            if (gr >= 0 && gr < HH && gc >= 0 && gc < WW) {
                const float* xp = x + ((size_t)(b * CI + ic0 + cp * 2) * HH + gr) * WW + gc;
                v0 = xp[0];
                v1 = xp[HH * WW];
            }
            int col = side ? 65 : 0;
            xs[(rr * 66 + col) * PXS + cp] =
                (int)((unsigned)f2bf(v0) | ((unsigned)f2bf(v1) << 16));
        }
        __syncthreads();
        const short* wfc = wfb + (size_t)ck * WF_CK;
        #pragma unroll
        for (int s = 0; s < 5; ++s) {
            const int xrow = wid + 1 + dh[s];
            const int xc0  = 1 + dw[s];
            v8s af[4];
            #pragma unroll
            for (int mt = 0; mt < 4; ++mt)
                af[mt] = *(const v8s*)(wfc + (size_t)((s * 4 + mt) * 4 + quad) * 128
                                           + l15 * 8);
            #pragma unroll
            for (int nt = 0; nt < 4; ++nt) {
                int px = xrow * 66 + nt * 16 + l15 + xc0;
                v4i bi = *(const v4i*)&xs[px * PXS + quad * 4];
                v8s bfr = __builtin_bit_cast(v8s, bi);
                #pragma unroll
                for (int mt = 0; mt < 4; ++mt)
                    acc[mt][nt] = __builtin_amdgcn_mfma_f32_16x16x32_bf16(
                        af[mt], bfr, acc[mt][nt], 0, 0, 0);
            }
        }
        __syncthreads();
    }
    #pragma unroll
    for (int mt = 0; mt < 4; ++mt)
        #pragma unroll
        for (int nt = 0; nt < 4; ++nt)
            #pragma unroll
            for (int r = 0; r < 4; ++r) {
                int o = oBase + mt * 16 + quad * 4 + r;
                int c = c0 + nt * 16 + l15;
                out[((size_t)(b * CO + o) * HH + row) * WW + c] = acc[mt][nt][r];
            }
}

// ================= R1 min fallback =================
__global__ __launch_bounds__(256) void demod_kernel(const float* __restrict__ y,
                                                    const float* __restrict__ wgt,
                                                    float* __restrict__ dbuf) {
    const int bo = blockIdx.x;
    const int b = bo >> 8, o = bo & 255;
    const int i = threadIdx.x;
    const float* wp = wgt + (o * CI + i) * 5;
    const float ym = y[b * CI + i] + 1.0f;
    float s2 = 0.f;
    #pragma unroll
    for (int s = 0; s < 5; ++s) { float w = wp[s]; s2 += w * w; }
    float val = ym * ym * s2;
    #pragma unroll
    for (int off = 32; off > 0; off >>= 1) val += __shfl_down(val, off);
    __shared__ float red[4];
    if ((threadIdx.x & 63) == 0) red[threadIdx.x >> 6] = val;
    __syncthreads();
    if (threadIdx.x == 0) dbuf[bo] = rsqrtf(red[0] + red[1] + red[2] + red[3] + 1e-6f);
}

__global__ __launch_bounds__(256) void conv_kernel_fb(const float* __restrict__ x,
                                                      const float* __restrict__ y,
                                                      const float* __restrict__ wgt,
                                                      const float* __restrict__ dbuf,
                                                      float* __restrict__ out) {
    const int b     = blockIdx.z;
    const int oBase = blockIdx.y * 64;
    const int st    = blockIdx.x;
    const int r0    = (st >> 1) * 4;
    const int c0    = (st & 1) * 64;
    const int tid  = threadIdx.x;
    const int wid  = tid >> 6;
    const int lane = tid & 63;
    const int l15  = lane & 15;
    const int quad = lane >> 4;
    __shared__ int   xs4[16 * 412];
    __shared__ short wlds[5 * 4 * 4 * 16 * 8];
    v4f acc[4][4];
    #pragma unroll
    for (int a = 0; a < 4; ++a)
        #pragma unroll
        for (int n = 0; n < 4; ++n) acc[a][n] = (v4f){0.f, 0.f, 0.f, 0.f};
    const int row = r0 + wid;
    for (int ic0 = 0; ic0 < CI; ic0 += 32) {
        for (int t = 0; t < 25; ++t) {
            int idx = tid + t * 256;
            if (idx < 6336) {
                int cp  = idx / 396;
                int rem = idx - cp * 396;
                int rr  = rem / 66;
                int cc  = rem - rr * 66;
                int gr  = r0 - 1 + rr;
                int gc  = c0 - 1 + cc;
                float v0 = 0.f, v1 = 0.f;
                if (gr >= 0 && gr < HH && gc >= 0 && gc < WW) {
                    const float* xp = x + ((size_t)(b * CI + ic0 + cp * 2) * HH + gr) * WW + gc;
                    v0 = xp[0];
                    v1 = xp[HH * WW];
                }
                xs4[cp * 412 + rr * 68 + cc] =
                    (int)((unsigned)f2bf(v0) | ((unsigned)f2bf(v1) << 16));
            }
        }
        #pragma unroll
        for (int p = 0; p < 8; ++p) {
            int pidx = tid + p * 256;
            int ol = pidx >> 5;
            int il = pidx & 31;
            int o  = oBase + ol;
            int ci = ic0 + il;
            float scale = (y[b * CI + ci] + 1.0f) * dbuf[b * CO + o];
            const float* wp = wgt + (o * CI + ci) * 5;
            int base = (((ol >> 4) * 4 + (il >> 3)) * 16 + (ol & 15)) * 8 + (il & 7);
            #pragma unroll
            for (int s = 0; s < 5; ++s)
                wlds[base + s * (4 * 4 * 16 * 8)] = (short)f2bf(wp[s] * scale);
        }
        __syncthreads();
        const int dh[5] = {-1, 0, 0, 0, 1};
        const int dw[5] = { 0,-1, 0, 1, 0};
        #pragma unroll
        for (int s = 0; s < 5; ++s) {
            int xrow = wid + 1 + dh[s];
            int xcb  = l15 + 1 + dw[s];
            v8s af[4];
            #pragma unroll
            for (int mt = 0; mt < 4; ++mt)
                af[mt] = *(const v8s*)&wlds[(((s * 4 + mt) * 4 + quad) * 16 + l15) * 8];
            #pragma unroll
            for (int nt = 0; nt < 4; ++nt) {
                v4i bi;
                #pragma unroll
                for (int p = 0; p < 4; ++p)
                    bi[p] = xs4[(quad * 4 + p) * 412 + xrow * 68 + nt * 16 + xcb];
                v8s bfr = __builtin_bit_cast(v8s, bi);
                #pragma unroll
                for (int mt = 0; mt < 4; ++mt)
                    acc[mt][nt] = __builtin_amdgcn_mfma_f32_16x16x32_bf16(
                        af[mt], bfr, acc[mt][nt], 0, 0, 0);
            }
        }
        __syncthreads();
    }
    #pragma unroll
    for (int mt = 0; mt < 4; ++mt)
        #pragma unroll
        for (int nt = 0; nt < 4; ++nt)
            #pragma unroll
            for (int r = 0; r < 4; ++r) {
                int o = oBase + mt * 16 + quad * 4 + r;
                int c = c0 + nt * 16 + l15;
                out[((size_t)(b * CO + o) * HH + row) * WW + c] = acc[mt][nt][r];
            }
}

extern "C" void kernel_launch(void* const* d_in, const int* in_sizes, int n_in,
                              void* d_out, int out_size, void* d_ws, size_t ws_size,
                              hipStream_t stream) {
    const float* x   = (const float*)d_in[0];
    const float* y   = (const float*)d_in[1];
    const float* wgt = (const float*)d_in[2];
    float* out = (float*)d_out;

    const size_t WF_BYTES = (size_t)BS * 4 * 8 * WF_CK * sizeof(short);  // 5.25 MB
    const size_t XT_OFF   = WF_BYTES + 8192;
    const size_t XT_BYTES = (size_t)BS * 8 * 16384 * 64;                 // 64 MB
    const size_t NEED_FULL = XT_OFF + XT_BYTES + 1024;                   // OOB slack
    const size_t NEED_MID  = WF_BYTES + 8192;

    short* wfrag = (short*)d_ws;

    if (ws_size >= NEED_FULL) {
        unsigned int* xt = (unsigned int*)((char*)d_ws + XT_OFF);
        prep_kernel<<<dim3(2048 + BS * 8 * HH), dim3(256), 0, stream>>>(
            x, y, wgt, wfrag, xt);
        conv3_kernel<<<dim3(64, CO / 64, BS), dim3(256), 0, stream>>>(
            (const char*)xt, wfrag, out);
    } else if (ws_size >= NEED_MID) {
        wprep2_kernel<<<dim3(BS * CO), dim3(256), 0, stream>>>(y, wgt, wfrag);
        conv_kernel<<<dim3(64, CO / 64, BS), dim3(256), 0, stream>>>(x, wfrag, out);
    } else {
        float* dbuf = (float*)d_ws;   // 8 KB
        demod_kernel<<<dim3(BS * CO), dim3(256), 0, stream>>>(y, wgt, dbuf);
        conv_kernel_fb<<<dim3(64, CO / 64, BS), dim3(256), 0, stream>>>(x, y, wgt, dbuf, out);
    }
}

// Round 5
// 312.813 us; speedup vs baseline: 1.0542x; 1.0542x over previous
//
#include <hip/hip_runtime.h>

// LatticeStyleConv R8: StyleGAN2-modulated 5-point stencil conv, bf16 MFMA.
// bs=8, ci=co=256, H=W=128.
//
// R8 = revert conv3 to the best-measured R3 structure (92.5-96us; 4 blk/CU,
// 2-barrier, LDS 33792B, VGPR 64) + batched prep (xprep 4 rows/block, grid
// 10240 -> 4096). R4-R7 established: dbuf/prefetch, 8x64 tile, counted-vmcnt,
// 5-phase+setprio, conflict-free LDS are ALL nulls-or-regressions for conv3;
// its floor in this form is ~92-95us (MFMA 99k + LDS 73k + VALU 57k cyc/CU
// serializing). Iteration accounting (dispatch timestamps): conv3 = 30% of
// dur_us; rest = prep + ~6 harness re-poison memsets (~150us fixed).
// Layouts (guide §3 m89/m91): A[m=l15][k=quad*8+j]; B[n=l15][k=quad*8+j];
// C/D col=l15, row=quad*4+reg.

typedef short v8s __attribute__((ext_vector_type(8)));
typedef float v4f __attribute__((ext_vector_type(4)));
typedef int   v4i __attribute__((ext_vector_type(4)));

#define BS 8
#define CI 256
#define CO 256
#define HH 128
#define WW 128

#define WF_CK 10240          // shorts per (b,ot,ck) A-frag slab
#define RSTR_B 5632          // conv3 LDS row stride bytes (88 px * 64B)
#define RSTR_I 1408          // ... in ints

#define GLOAD_LDS16(g, l)                                                  \
    __builtin_amdgcn_global_load_lds(                                      \
        (__attribute__((address_space(1))) void*)(g),                      \
        (__attribute__((address_space(3))) void*)(l), 16, 0, 0)

__device__ __forceinline__ unsigned short f2bf(float f) {
    unsigned u = __builtin_bit_cast(unsigned, f);
    u += 0x7FFFu + ((u >> 16) & 1u);   // RNE (inputs finite)
    return (unsigned short)(u >> 16);
}

// -------- fused prep: blocks [0,2048) weight-prep, [2048,4096) x-transpose --
__global__ __launch_bounds__(256) void prep_kernel(const float* __restrict__ x,
                                                   const float* __restrict__ y,
                                                   const float* __restrict__ wgt,
                                                   short* __restrict__ wfrag,
                                                   unsigned int* __restrict__ xt) {
    __shared__ float tr[32 * 132];     // [c][px], stride 132 floats
    __shared__ float red[4];

    if (blockIdx.x < 2048) {
        // ---- wprep2: fused demod + modulated weights -> A-frag layout ----
        const int bo = blockIdx.x;
        const int b = bo >> 8, o = bo & 255;
        const int ci = threadIdx.x;
        const float ym = y[b * CI + ci] + 1.0f;
        const float* wp = wgt + (o * CI + ci) * 5;
        float w[5];
        float s2 = 0.f;
        #pragma unroll
        for (int s = 0; s < 5; ++s) { w[s] = wp[s]; s2 += w[s] * w[s]; }
        float ss = ym * ym * s2;
        #pragma unroll
        for (int off = 32; off > 0; off >>= 1) ss += __shfl_down(ss, off);
        if ((threadIdx.x & 63) == 0) red[threadIdx.x >> 6] = ss;
        __syncthreads();
        const float tot = red[0] + red[1] + red[2] + red[3];
        const float scale = ym * rsqrtf(tot + 1e-6f);
        const int ot = o >> 6, mt = (o >> 4) & 3, m = o & 15;
        const int ck = ci >> 5, quad = (ci >> 3) & 3, j = ci & 7;
        size_t base = ((size_t)(b * 4 + ot) * 8 + ck) * WF_CK + quad * 128 + m * 8 + j;
        #pragma unroll
        for (int s = 0; s < 5; ++s)
            wfrag[base + (size_t)(s * 4 + mt) * 512] = (short)f2bf(w[s] * scale);
    } else {
        // ---- xprep: x fp32 [b][ci][h][w] -> bf16 x_t[b][ck][h][w][32ch] ----
        // 4 rows per block: bid = (b*8 + ck)*32 + h4, rows h4*4 .. h4*4+3
        const int bid = blockIdx.x - 2048;
        const int b  = bid >> 8;
        const int ck = (bid >> 5) & 7;
        const int h4 = bid & 31;
        const int tid = threadIdx.x;
        #pragma unroll
        for (int r = 0; r < 4; ++r) {
            const int h = h4 * 4 + r;
            // vectorized loads: 4 x dwordx4 per thread, b128 LDS writes
            #pragma unroll
            for (int i = 0; i < 4; ++i) {
                int q  = tid + i * 256;            // 0..1023
                int c  = q >> 5;                   // 0..31
                int qp = q & 31;                   // 0..31 (px quad)
                v4f v = *(const v4f*)&x[((size_t)(b * CI + ck * 32 + c) * HH + h) * WW
                                        + qp * 4];
                *(v4f*)&tr[c * 132 + qp * 4] = v;
            }
            __syncthreads();
            const int px = tid >> 1, half = tid & 1;
            unsigned pk[8];
            #pragma unroll
            for (int k = 0; k < 8; ++k) {
                float f0 = tr[(half * 16 + 2 * k)     * 132 + px];
                float f1 = tr[(half * 16 + 2 * k + 1) * 132 + px];
                pk[k] = (unsigned)f2bf(f0) | ((unsigned)f2bf(f1) << 16);
            }
            unsigned int* dst = xt + ((size_t)((b * 8 + ck) * 16384 + h * 128 + px)) * 16
                                   + half * 8;
            *(v4i*)dst       = (v4i){(int)pk[0], (int)pk[1], (int)pk[2], (int)pk[3]};
            *(v4i*)(dst + 4) = (v4i){(int)pk[4], (int)pk[5], (int)pk[6], (int)pk[7]};
            __syncthreads();   // protect tr before next row's writes
        }
    }
}

// -------- wprep2 standalone (mid-path fallback) --------
__global__ __launch_bounds__(256) void wprep2_kernel(const float* __restrict__ y,
                                                     const float* __restrict__ wgt,
                                                     short* __restrict__ wfrag) {
    const int bo = blockIdx.x;
    const int b = bo >> 8, o = bo & 255;
    const int ci = threadIdx.x;
    const float ym = y[b * CI + ci] + 1.0f;
    const float* wp = wgt + (o * CI + ci) * 5;
    float w[5];
    float s2 = 0.f;
    #pragma unroll
    for (int s = 0; s < 5; ++s) { w[s] = wp[s]; s2 += w[s] * w[s]; }
    float ss = ym * ym * s2;
    #pragma unroll
    for (int off = 32; off > 0; off >>= 1) ss += __shfl_down(ss, off);
    __shared__ float red[4];
    if ((threadIdx.x & 63) == 0) red[threadIdx.x >> 6] = ss;
    __syncthreads();
    const float tot = red[0] + red[1] + red[2] + red[3];
    const float scale = ym * rsqrtf(tot + 1e-6f);
    const int ot = o >> 6, mt = (o >> 4) & 3, m = o & 15;
    const int ck = ci >> 5, quad = (ci >> 3) & 3, j = ci & 7;
    size_t base = ((size_t)(b * 4 + ot) * 8 + ck) * WF_CK + quad * 128 + m * 8 + j;
    #pragma unroll
    for (int s = 0; s < 5; ++s)
        wfrag[base + (size_t)(s * 4 + mt) * 512] = (short)f2bf(w[s] * scale);
}

// -------- conv3: async-staged x, A from global, MFMA (R3 verbatim) --------
__global__ __launch_bounds__(256, 4) void conv3_kernel(const char* __restrict__ xt,
                                                       const short* __restrict__ wfrag,
                                                       float* __restrict__ out) {
    const int b     = blockIdx.z;
    const int ot    = blockIdx.y;
    const int oBase = ot * 64;
    const int st    = blockIdx.x;          // 32 row-tiles x 2 col-tiles
    const int r0    = (st >> 1) * 4;
    const int c0    = (st & 1) * 64;
    const bool left = (c0 == 0);

    const int tid  = threadIdx.x;
    const int wid  = tid >> 6;
    const int lane = tid & 63;
    const int l15  = lane & 15;
    const int quad = lane >> 4;

    __shared__ __align__(16) int xs[6 * RSTR_I];    // 33792 B

    v4f acc[4][4];
    #pragma unroll
    for (int a = 0; a < 4; ++a)
        #pragma unroll
        for (int n = 0; n < 4; ++n) acc[a][n] = (v4f){0.f, 0.f, 0.f, 0.f};

    // ---- one-time zeroing of never-loaded halo regions ----
    const v4i z4 = (v4i){0, 0, 0, 0};
    if (r0 == 0)
        for (int i = tid; i < 264; i += 256) *(v4i*)&xs[i * 4] = z4;                 // row 0, px0..65
    if (r0 == HH - 4)
        for (int i = tid; i < 264; i += 256) *(v4i*)&xs[5 * RSTR_I + i * 4] = z4;    // row 5
    if (left && tid < 24) *(v4i*)&xs[(tid >> 2) * RSTR_I + (tid & 3) * 4] = z4;      // px0 col
    // first chunk's __syncthreads covers these writes

    const int row = r0 + wid;
    const short* wfb = wfrag + (size_t)(b * 4 + ot) * 8 * WF_CK;
    const bool rz = (!left) && (l15 == 15);          // right-edge gc=128 mask
    const int gstartB = left ? 0 : (c0 - 1) * 64;    // byte offset of first loaded px
    const int lshift  = left ? 64 : 0;

    const int dh[5] = {-1, 0, 0, 0, 1};
    const int dw[5] = { 0,-1, 0, 1, 0};

    for (int ck = 0; ck < 8; ++ck) {
        const char* planep = xt + (((size_t)(b * 8 + ck)) << 20);
        // ---- async staging: rows rr in {wid, wid+4}, 5x1024B per row ----
        #pragma unroll
        for (int rsel = 0; rsel < 2; ++rsel) {
            int rr = wid + rsel * 4;
            if (rr < 6) {
                bool skip = (r0 == 0 && rr == 0) || (r0 == HH - 4 && rr == 5);
                if (!skip) {
                    int gr = r0 - 1 + rr;
                    const char* gb = planep + (size_t)gr * 8192 + gstartB + lane * 16;
                    char* lb = (char*)xs + rr * RSTR_B + lshift;
                    #pragma unroll
                    for (int t = 0; t < 5; ++t)
                        GLOAD_LDS16(gb + t * 1024, lb + t * 1024);
                }
            }
        }
        __syncthreads();   // drains vmcnt: x tile ready

        const short* wfc = wfb + (size_t)ck * WF_CK;
        #pragma unroll
        for (int s = 0; s < 5; ++s) {
            const int xrow = wid + 1 + dh[s];
            const int xc0  = 1 + dw[s];
            v8s af[4];
            #pragma unroll
            for (int mt = 0; mt < 4; ++mt)
                af[mt] = *(const v8s*)(wfc + (size_t)((s * 4 + mt) * 4 + quad) * 128
                                           + l15 * 8);
            #pragma unroll
            for (int nt = 0; nt < 4; ++nt) {
                v4i bi = *(const v4i*)&xs[xrow * RSTR_I + (nt * 16 + l15 + xc0) * 16
                                          + quad * 4];
                if (s == 3 && nt == 3) { if (rz) bi = z4; }   // gc=128 -> 0
                v8s bfr = __builtin_bit_cast(v8s, bi);
                #pragma unroll
                for (int mt = 0; mt < 4; ++mt)
                    acc[mt][nt] = __builtin_amdgcn_mfma_f32_16x16x32_bf16(
                        af[mt], bfr, acc[mt][nt], 0, 0, 0);
            }
        }
        __syncthreads();   // protect xs before next chunk's DMA
    }

    #pragma unroll
    for (int mt = 0; mt < 4; ++mt)
        #pragma unroll
        for (int nt = 0; nt < 4; ++nt)
            #pragma unroll
            for (int r = 0; r < 4; ++r) {
                int o = oBase + mt * 16 + quad * 4 + r;
                int c = c0 + nt * 16 + l15;
                out[((size_t)(b * CO + o) * HH + row) * WW + c] = acc[mt][nt][r];
            }
}

// ================= R2 conv (mid fallback) =================
__global__ __launch_bounds__(256, 4) void conv_kernel(const float* __restrict__ x,
                                                      const short* __restrict__ wfrag,
                                                      float* __restrict__ out) {
    const int b     = blockIdx.z;
    const int ot    = blockIdx.y;
    const int oBase = ot * 64;
    const int st    = blockIdx.x;
    const int r0    = (st >> 1) * 4;
    const int c0    = (st & 1) * 64;
    const int tid  = threadIdx.x;
    const int wid  = tid >> 6;
    const int lane = tid & 63;
    const int l15  = lane & 15;
    const int quad = lane >> 4;
    #define PXS 20
    __shared__ __align__(16) int xs[6 * 66 * PXS];
    v4f acc[4][4];
    #pragma unroll
    for (int a = 0; a < 4; ++a)
        #pragma unroll
        for (int n = 0; n < 4; ++n) acc[a][n] = (v4f){0.f, 0.f, 0.f, 0.f};
    const int row = r0 + wid;
    const short* wfb = wfrag + (size_t)(b * 4 + ot) * 8 * WF_CK;
    const int dh[5] = {-1, 0, 0, 0, 1};
    const int dw[5] = { 0,-1, 0, 1, 0};
    for (int ck = 0; ck < 8; ++ck) {
        const int ic0 = ck * 32;
        #pragma unroll
        for (int t = 0; t < 6; ++t) {
            int idx = tid + t * 256;
            int cp  = idx & 15;
            int tmp = idx >> 4;
            int cq  = tmp & 15;
            int rr  = tmp >> 4;
            int gr  = r0 - 1 + rr;
            v4f a0 = (v4f){0.f, 0.f, 0.f, 0.f}, a1 = a0;
            if (gr >= 0 && gr < HH) {
                const float* xp = x + ((size_t)(b * CI + ic0 + cp * 2) * HH + gr) * WW
                                    + (c0 + cq * 4);
                a0 = *(const v4f*)xp;
                a1 = *(const v4f*)(xp + HH * WW);
            }
            int base = (rr * 66 + cq * 4 + 1) * PXS + cp;
            #pragma unroll
            for (int k = 0; k < 4; ++k)
                xs[base + k * PXS] =
                    (int)((unsigned)f2bf(a0[k]) | ((unsigned)f2bf(a1[k]) << 16));
        }
        if (tid < 192) {
            int cp   = tid & 15;
            int tmp  = tid >> 4;
            int side = (tmp >= 6) ? 1 : 0;
            int rr   = tmp - 6 * side;
            int gr   = r0 - 1 + rr;
            int gc   = side ? (c0 + 64) : (c0 - 1);
            float v0 = 0.f, v1 = 0.f;
            if (gr >= 0 && gr < HH && gc >= 0 && gc < WW) {
                const float* xp = x + ((size_t)(b * CI + ic0 + cp * 2) * HH + gr) * WW + gc;
                v0 = xp[0];
                v1 = xp[HH * WW];
            }
            int col = side ? 65 : 0;
            xs[(rr * 66 + col) * PXS + cp] =
                (int)((unsigned)f2bf(v0) | ((unsigned)f2bf(v1) << 16));
        }
        __syncthreads();
        const short* wfc = wfb + (size_t)ck * WF_CK;
        #pragma unroll
        for (int s = 0; s < 5; ++s) {
            const int xrow = wid + 1 + dh[s];
            const int xc0  = 1 + dw[s];
            v8s af[4];
            #pragma unroll
            for (int mt = 0; mt < 4; ++mt)
                af[mt] = *(const v8s*)(wfc + (size_t)((s * 4 + mt) * 4 + quad) * 128
                                           + l15 * 8);
            #pragma unroll
            for (int nt = 0; nt < 4; ++nt) {
                int px = xrow * 66 + nt * 16 + l15 + xc0;
                v4i bi = *(const v4i*)&xs[px * PXS + quad * 4];
                v8s bfr = __builtin_bit_cast(v8s, bi);
                #pragma unroll
                for (int mt = 0; mt < 4; ++mt)
                    acc[mt][nt] = __builtin_amdgcn_mfma_f32_16x16x32_bf16(
                        af[mt], bfr, acc[mt][nt], 0, 0, 0);
            }
        }
        __syncthreads();
    }
    #pragma unroll
    for (int mt = 0; mt < 4; ++mt)
        #pragma unroll
        for (int nt = 0; nt < 4; ++nt)
            #pragma unroll
            for (int r = 0; r < 4; ++r) {
                int o = oBase + mt * 16 + quad * 4 + r;
                int c = c0 + nt * 16 + l15;
                out[((size_t)(b * CO + o) * HH + row) * WW + c] = acc[mt][nt][r];
            }
}

// ================= R1 min fallback =================
__global__ __launch_bounds__(256) void demod_kernel(const float* __restrict__ y,
                                                    const float* __restrict__ wgt,
                                                    float* __restrict__ dbuf) {
    const int bo = blockIdx.x;
    const int b = bo >> 8, o = bo & 255;
    const int i = threadIdx.x;
    const float* wp = wgt + (o * CI + i) * 5;
    const float ym = y[b * CI + i] + 1.0f;
    float s2 = 0.f;
    #pragma unroll
    for (int s = 0; s < 5; ++s) { float w = wp[s]; s2 += w * w; }
    float val = ym * ym * s2;
    #pragma unroll
    for (int off = 32; off > 0; off >>= 1) val += __shfl_down(val, off);
    __shared__ float red[4];
    if ((threadIdx.x & 63) == 0) red[threadIdx.x >> 6] = val;
    __syncthreads();
    if (threadIdx.x == 0) dbuf[bo] = rsqrtf(red[0] + red[1] + red[2] + red[3] + 1e-6f);
}

__global__ __launch_bounds__(256) void conv_kernel_fb(const float* __restrict__ x,
                                                      const float* __restrict__ y,
                                                      const float* __restrict__ wgt,
                                                      const float* __restrict__ dbuf,
                                                      float* __restrict__ out) {
    const int b     = blockIdx.z;
    const int oBase = blockIdx.y * 64;
    const int st    = blockIdx.x;
    const int r0    = (st >> 1) * 4;
    const int c0    = (st & 1) * 64;
    const int tid  = threadIdx.x;
    const int wid  = tid >> 6;
    const int lane = tid & 63;
    const int l15  = lane & 15;
    const int quad = lane >> 4;
    __shared__ int   xs4[16 * 412];
    __shared__ short wlds[5 * 4 * 4 * 16 * 8];
    v4f acc[4][4];
    #pragma unroll
    for (int a = 0; a < 4; ++a)
        #pragma unroll
        for (int n = 0; n < 4; ++n) acc[a][n] = (v4f){0.f, 0.f, 0.f, 0.f};
    const int row = r0 + wid;
    for (int ic0 = 0; ic0 < CI; ic0 += 32) {
        for (int t = 0; t < 25; ++t) {
            int idx = tid + t * 256;
            if (idx < 6336) {
                int cp  = idx / 396;
                int rem = idx - cp * 396;
                int rr  = rem / 66;
                int cc  = rem - rr * 66;
                int gr  = r0 - 1 + rr;
                int gc  = c0 - 1 + cc;
                float v0 = 0.f, v1 = 0.f;
                if (gr >= 0 && gr < HH && gc >= 0 && gc < WW) {
                    const float* xp = x + ((size_t)(b * CI + ic0 + cp * 2) * HH + gr) * WW + gc;
                    v0 = xp[0];
                    v1 = xp[HH * WW];
                }
                xs4[cp * 412 + rr * 68 + cc] =
                    (int)((unsigned)f2bf(v0) | ((unsigned)f2bf(v1) << 16));
            }
        }
        #pragma unroll
        for (int p = 0; p < 8; ++p) {
            int pidx = tid + p * 256;
            int ol = pidx >> 5;
            int il = pidx & 31;
            int o  = oBase + ol;
            int ci = ic0 + il;
            float scale = (y[b * CI + ci] + 1.0f) * dbuf[b * CO + o];
            const float* wp = wgt + (o * CI + ci) * 5;
            int base = (((ol >> 4) * 4 + (il >> 3)) * 16 + (ol & 15)) * 8 + (il & 7);
            #pragma unroll
            for (int s = 0; s < 5; ++s)
                wlds[base + s * (4 * 4 * 16 * 8)] = (short)f2bf(wp[s] * scale);
        }
        __syncthreads();
        const int dh[5] = {-1, 0, 0, 0, 1};
        const int dw[5] = { 0,-1, 0, 1, 0};
        #pragma unroll
        for (int s = 0; s < 5; ++s) {
            int xrow = wid + 1 + dh[s];
            int xcb  = l15 + 1 + dw[s];
            v8s af[4];
            #pragma unroll
            for (int mt = 0; mt < 4; ++mt)
                af[mt] = *(const v8s*)&wlds[(((s * 4 + mt) * 4 + quad) * 16 + l15) * 8];
            #pragma unroll
            for (int nt = 0; nt < 4; ++nt) {
                v4i bi;
                #pragma unroll
                for (int p = 0; p < 4; ++p)
                    bi[p] = xs4[(quad * 4 + p) * 412 + xrow * 68 + nt * 16 + xcb];
                v8s bfr = __builtin_bit_cast(v8s, bi);
                #pragma unroll
                for (int mt = 0; mt < 4; ++mt)
                    acc[mt][nt] = __builtin_amdgcn_mfma_f32_16x16x32_bf16(
                        af[mt], bfr, acc[mt][nt], 0, 0, 0);
            }
        }
        __syncthreads();
    }
    #pragma unroll
    for (int mt = 0; mt < 4; ++mt)
        #pragma unroll
        for (int nt = 0; nt < 4; ++nt)
            #pragma unroll
            for (int r = 0; r < 4; ++r) {
                int o = oBase + mt * 16 + quad * 4 + r;
                int c = c0 + nt * 16 + l15;
                out[((size_t)(b * CO + o) * HH + row) * WW + c] = acc[mt][nt][r];
            }
}

extern "C" void kernel_launch(void* const* d_in, const int* in_sizes, int n_in,
                              void* d_out, int out_size, void* d_ws, size_t ws_size,
                              hipStream_t stream) {
    const float* x   = (const float*)d_in[0];
    const float* y   = (const float*)d_in[1];
    const float* wgt = (const float*)d_in[2];
    float* out = (float*)d_out;

    const size_t WF_BYTES = (size_t)BS * 4 * 8 * WF_CK * sizeof(short);  // 5.25 MB
    const size_t XT_OFF   = WF_BYTES + 8192;
    const size_t XT_BYTES = (size_t)BS * 8 * 16384 * 64;                 // 64 MB
    const size_t NEED_FULL = XT_OFF + XT_BYTES + 1024;                   // OOB slack
    const size_t NEED_MID  = WF_BYTES + 8192;

    short* wfrag = (short*)d_ws;

    if (ws_size >= NEED_FULL) {
        unsigned int* xt = (unsigned int*)((char*)d_ws + XT_OFF);
        prep_kernel<<<dim3(2048 + BS * 8 * 32), dim3(256), 0, stream>>>(
            x, y, wgt, wfrag, xt);
        conv3_kernel<<<dim3(64, CO / 64, BS), dim3(256), 0, stream>>>(
            (const char*)xt, wfrag, out);
    } else if (ws_size >= NEED_MID) {
        wprep2_kernel<<<dim3(BS * CO), dim3(256), 0, stream>>>(y, wgt, wfrag);
        conv_kernel<<<dim3(64, CO / 64, BS), dim3(256), 0, stream>>>(x, wfrag, out);
    } else {
        float* dbuf = (float*)d_ws;   // 8 KB
        demod_kernel<<<dim3(BS * CO), dim3(256), 0, stream>>>(y, wgt, dbuf);
        conv_kernel_fb<<<dim3(64, CO / 64, BS), dim3(256), 0, stream>>>(x, y, wgt, dbuf, out);
    }
}